// Round 1
// baseline (247.112 us; speedup 1.0000x reference)
//
#include <hip/hip_runtime.h>
#include <hip/hip_bf16.h>
#include <hip/hip_fp16.h>

// Problem: B=4096, D=1024, H=8192, O=1000
//   winners[b] = argmin_h ||x_b - k_h||  (== argmax dot, k rows unit-norm)
//   output[b,o] = G[o, winners[b]]
// Pipeline (3 dispatches; measured fixed replay overhead ~75 us, R6 coop probe):
//   1) cvt: fp32 -> fp8(e4m3) for x,kw (4 rows/block) + parallel G->Gt transpose
//   2) gemm_top2: MX-fp8 MFMA scores (16x16x128 f8f6f4, unit e8m0 scales ->
//      numerically identical to non-scaled fp8 at 2x rate), BK=128, 16B-granular
//      XOR-swizzle chunk^(row&7): quarter-wave-conflict-free ds_read_b128,
//      top-2 packed keys per (row, 64-col half-tile) -> uint4 per (row, 128-tile)
//   3) select: wave-per-row exact fp64 refinement (margin 0.35 >> fp8 dot err
//      ~0.05) + fused coalesced gather.

#define BB 4096
#define DD 1024
#define HH 8192
#define OO 1000

#define BM 128
#define BN 128
#define BK 128         // bytes == elements (fp8)
#define NTILES (HH / BN)   // 64

typedef _Float16 f16;
typedef float f32x4 __attribute__((ext_vector_type(4)));
typedef int v8i __attribute__((ext_vector_type(8)));
typedef int v4i __attribute__((ext_vector_type(4)));
union Frag { v8i v; v4i h[2]; };

typedef __attribute__((address_space(3))) uint32_t lds_u32_t;
typedef __attribute__((address_space(1))) uint32_t glb_u32_t;

// ---- packed key: monotone(float) with low 7 bits = tile-local column ----
__device__ __forceinline__ uint32_t packkey(float v, int col) {
  uint32_t u = __float_as_uint(v);
  uint32_t mask = (uint32_t)((int32_t)u >> 31) | 0x80000000u;
  u ^= mask;                       // monotone: bigger float -> bigger uint
  return (u & 0xFFFFFF80u) | (uint32_t)col;
}
__device__ __forceinline__ float unpackval(uint32_t k) {
  uint32_t u = k & 0xFFFFFF80u;
  uint32_t mask = (k & 0x80000000u) ? 0x80000000u : 0xFFFFFFFFu;
  return __uint_as_float(u ^ mask);
}
__device__ __forceinline__ void kmerge(uint32_t& k1, uint32_t& k2,
                                       uint32_t o1, uint32_t o2) {
  uint32_t mn = min(k1, o1);
  uint32_t alt = (k1 > o1) ? k2 : o2;
  k1 = max(k1, o1);
  k2 = max(mn, alt);
}

// -------- cvt: fp32 -> fp8 e4m3 (4 rows/block) + parallel transpose ---------
// blocks [0, 3072): 4 rows each of x (rows 0..BB-1) then kw (rows BB..BB+HH-1)
// blocks [3072, 3072+2048): 4 parallel 32x32 transpose tiles of G -> Gt
__global__ __launch_bounds__(256) void cvt_kernel(
    const float* __restrict__ x, const float* __restrict__ kw,
    uint8_t* __restrict__ xq, uint8_t* __restrict__ kq,
    const float* __restrict__ G, float* __restrict__ Gt) {
  const int tid = threadIdx.x;
  const int blk = blockIdx.x;
  __shared__ float tile[32][33];
  if (blk < (BB + HH) / 4) {
#pragma unroll
    for (int i = 0; i < 4; ++i) {
      int r = blk * 4 + i;
      const float* src = (r < BB) ? (x + (size_t)r * DD)
                                  : (kw + (size_t)(r - BB) * DD);
      uint8_t* dst = (r < BB) ? (xq + (size_t)r * DD)
                              : (kq + (size_t)(r - BB) * DD);
      float4 v = ((const float4*)src)[tid];
      int p = 0;
      p = __builtin_amdgcn_cvt_pk_fp8_f32(v.x, v.y, p, false);  // bytes 0,1
      p = __builtin_amdgcn_cvt_pk_fp8_f32(v.z, v.w, p, true);   // bytes 2,3
      ((int*)dst)[tid] = p;
    }
  } else {
    if (Gt == nullptr) return;
    const int tb = blk - (BB + HH) / 4;
    const int tx = tid & 31;
    const int ty = tid >> 5;  // 0..7
#pragma unroll 1
    for (int j4 = 0; j4 < 4; ++j4) {
      int tile_id = tb * 4 + j4;       // 0..8191
      int h0 = (tile_id >> 5) * 32;
      int o0 = (tile_id & 31) * 32;
      __syncthreads();
#pragma unroll
      for (int j = 0; j < 4; ++j) {
        int o = o0 + ty + j * 8;
        if (o < OO) tile[ty + j * 8][tx] = G[(size_t)o * HH + h0 + tx];
      }
      __syncthreads();
#pragma unroll
      for (int j = 0; j < 4; ++j) {
        int o = o0 + tx;
        int h = h0 + ty + j * 8;
        if (o < OO) Gt[(size_t)h * OO + o] = tile[tx][ty + j * 8];
      }
    }
  }
}

// ------------- GEMM (MX-fp8 scores) + top-2 keys per half-tile --------------
// A = xq [B][D] fp8, Bt = kq [H][D] fp8 (NT). Block: 128x128 C-tile, BK=128
// (8 K-iters, 16 mfma_scale_16x16x128 + 16 ds_read_b128 per iter,
//  8 global_load_lds/iter/thread).
// LDS swizzle at 16B granularity: LDS 16B-chunk (row, c16) holds source chunk
// c16 ^ (row&7). Writer (global_load_lds) stays lane-linear in LDS with
// 16B-contiguous sources; reader: per quarter-wave (lq fixed, lm 0..15) chunk
// index 2lq^(lm&7) is a permutation of 0..7 over row classes -> 2 accesses per
// bank per 2-cycle window = conflict-free (m136: 2-way free).
__global__ __launch_bounds__(256) void gemm_top2(
    const uint8_t* __restrict__ A, const uint8_t* __restrict__ Bt,
    uint4* __restrict__ pk) {
  __shared__ __align__(16) uint8_t sA[BM * BK];  // 16 KB
  __shared__ __align__(16) uint8_t sB[BN * BK];  // 16 KB
  __shared__ uint2 mk[128][2];                   // 2 KB

  const int tid = threadIdx.x;
  const int w = tid >> 6;       // wave 0..3
  const int L = tid & 63;       // lane
  const int m0 = blockIdx.y * BM;
  const int n0 = blockIdx.x * BN;
  const int rm = (w >> 1) * 64;  // wave row base within tile
  const int cn = (w & 1) * 64;   // wave col base within tile

  f32x4 acc[4][4];
#pragma unroll
  for (int i = 0; i < 4; ++i)
#pragma unroll
    for (int j = 0; j < 4; ++j) {
      acc[i][j][0] = 0.f; acc[i][j][1] = 0.f; acc[i][j][2] = 0.f; acc[i][j][3] = 0.f;
    }

  const int lm = L & 15;    // fragment row within 16
  const int lq = L >> 4;    // quad: k-block of 32 elements

  // staging: thread owns LDS 16B-chunks c = tid + 256*j, j=0..3 (per matrix).
  // chunk c: row = c>>3, c16 = c&7, source 16B-chunk = c16 ^ (row&7).
  const uint8_t* pA[4];
  const uint8_t* pB[4];
  int dst[4];
#pragma unroll
  for (int j = 0; j < 4; ++j) {
    int c = tid + 256 * j;
    int r = c >> 3;
    int so = ((c & 7) ^ (r & 7)) * 16;
    pA[j] = A + (size_t)(m0 + r) * DD + so;
    pB[j] = Bt + (size_t)(n0 + r) * DD + so;
    dst[j] = c * 16;
  }

  // fragment read: lane (lm, lq) needs logical 16B-chunks {2lq, 2lq+1} of its
  // row (32 contiguous K-bytes = one MX scale block). phys chunk = logical ^ s.
  const int s = lm & 7;
  const int o_lo = ((2 * lq) ^ s) * 16;
  const int o_hi = ((2 * lq + 1) ^ s) * 16;
  const int raBase = (rm + lm) * BK;
  const int rbBase = (cn + lm) * BK;

  for (int kt = 0; kt < DD / BK; ++kt) {
    __syncthreads();  // prev compute done before overwriting LDS
#pragma unroll
    for (int j = 0; j < 4; ++j) {
      __builtin_amdgcn_global_load_lds((const glb_u32_t*)pA[j], (lds_u32_t*)(sA + dst[j]), 16, 0, 0);
      __builtin_amdgcn_global_load_lds((const glb_u32_t*)pB[j], (lds_u32_t*)(sB + dst[j]), 16, 0, 0);
      pA[j] += BK; pB[j] += BK;
    }
    __syncthreads();  // drains vmcnt before use

    Frag af[4], bf[4];
#pragma unroll
    for (int i = 0; i < 4; ++i) {
      const uint8_t* base = sA + raBase + i * 16 * BK;
      af[i].h[0] = *(const v4i*)(base + o_lo);
      af[i].h[1] = *(const v4i*)(base + o_hi);
    }
#pragma unroll
    for (int j = 0; j < 4; ++j) {
      const uint8_t* base = sB + rbBase + j * 16 * BK;
      bf[j].h[0] = *(const v4i*)(base + o_lo);
      bf[j].h[1] = *(const v4i*)(base + o_hi);
    }
#pragma unroll
    for (int i = 0; i < 4; ++i)
#pragma unroll
      for (int j = 0; j < 4; ++j)
        acc[i][j] = __builtin_amdgcn_mfma_scale_f32_16x16x128_f8f6f4(
            af[i].v, bf[j].v, acc[i][j],
            0 /*A fmt fp8*/, 0 /*B fmt fp8*/,
            0, 0x7F7F7F7Fu /*unit e8m0 scale A*/,
            0, 0x7F7F7F7Fu /*unit e8m0 scale B*/);
  }

  // Epilogue: per-row top-2 over this wave's 64-col half (packed keys).
  // C/D layout (16x16, shape-determined): col = lane&15, row = (lane>>4)*4 + reg.
  const int col0 = cn + lm;
#pragma unroll
  for (int i = 0; i < 4; ++i) {
#pragma unroll
    for (int r = 0; r < 4; ++r) {
      uint32_t k1 = 0, k2 = 0;
#pragma unroll
      for (int j = 0; j < 4; ++j) {
        uint32_t kj = packkey(acc[i][j][r], col0 + j * 16);
        if (kj > k1) { k2 = k1; k1 = kj; }
        else k2 = max(k2, kj);
      }
#pragma unroll
      for (int msk = 1; msk < 16; msk <<= 1) {
        uint32_t o1 = (uint32_t)__shfl_xor((int)k1, msk, 64);
        uint32_t o2 = (uint32_t)__shfl_xor((int)k2, msk, 64);
        kmerge(k1, k2, o1, o2);
      }
      if (lm == 0) {
        int rl = rm + i * 16 + lq * 4 + r;
        mk[rl][w & 1] = make_uint2(k1, k2);
      }
    }
  }
  __syncthreads();
  if (tid < 128) {
    uint2 a = mk[tid][0], b = mk[tid][1];  // keep both halves: top-2 per 64 cols
    pk[(size_t)(m0 + tid) * NTILES + blockIdx.x] = make_uint4(a.x, a.y, b.x, b.y);
  }
}

// ------- select: wave-per-row exact fp64 refinement + fused gather ----------
// One 64-lane wave per x-row; 4 rows per 256-thread block. No __syncthreads.
__global__ __launch_bounds__(256) void select_kernel(
    const float* __restrict__ x, const float* __restrict__ kw,
    const uint4* __restrict__ pk,
    const float* __restrict__ Gt, const float* __restrict__ G,
    float* __restrict__ out, float* __restrict__ out_w) {
  const int b = blockIdx.x * 4 + (threadIdx.x >> 6);
  const int L = threadIdx.x & 63;

  // x row: 16 floats/lane (4 x float4, coalesced)
  const float4* x4 = (const float4*)(x + (size_t)b * DD);
  float4 xv[4];
#pragma unroll
  for (int j = 0; j < 4; ++j) xv[j] = x4[L + 64 * j];

  // keys of tile L: top-2 of each 64-col half (k.x>=k.y, k.z>=k.w)
  uint4 kp = pk[(size_t)b * NTILES + L];

  // x2 in fp64 (xor-reduce -> all lanes hold total)
  double x2 = 0.0;
#pragma unroll
  for (int j = 0; j < 4; ++j)
    x2 += (double)xv[j].x * xv[j].x + (double)xv[j].y * xv[j].y +
          (double)xv[j].z * xv[j].z + (double)xv[j].w * xv[j].w;
#pragma unroll
  for (int msk = 1; msk < 64; msk <<= 1) x2 += __shfl_xor(x2, msk, 64);

  // global max key -> margin threshold (fp8 dot err rms ~0.05; 0.35 >= 5 sigma)
  uint32_t m = max(kp.x, kp.z);
#pragma unroll
  for (int msk = 1; msk < 64; msk <<= 1)
    m = max(m, (uint32_t)__shfl_xor((int)m, msk, 64));
  const uint32_t thrk = packkey(unpackval(m) - 0.35f, 0);

  unsigned long long cand[4];
  cand[0] = __ballot(kp.x >= thrk);
  cand[1] = __ballot(kp.y >= thrk);
  cand[2] = __ballot(kp.z >= thrk);
  cand[3] = __ballot(kp.w >= thrk);

  double best = 1e300;
  int bestc = 0x7fffffff;
#pragma unroll 1
  for (int pass = 0; pass < 4; ++pass) {
    unsigned long long bits = cand[pass];
    uint32_t mykey = (pass == 0) ? kp.x : (pass == 1) ? kp.y
                    : (pass == 2) ? kp.z : kp.w;
    while (bits) {
      int tt = __ffsll((long long)bits) - 1;   // candidate's tile = lane tt
      bits &= bits - 1;
      uint32_t kbt = (uint32_t)__shfl((int)mykey, tt, 64);
      int col = tt * 128 + (int)(kbt & 127u);
      const float4* k4 = (const float4*)(kw + (size_t)col * DD);
      double dot = 0.0, w2 = 0.0;
#pragma unroll
      for (int j = 0; j < 4; ++j) {
        float4 wv = k4[L + 64 * j];
        dot += (double)xv[j].x * wv.x + (double)xv[j].y * wv.y +
               (double)xv[j].z * wv.z + (double)xv[j].w * wv.w;
        w2 += (double)wv.x * wv.x + (double)wv.y * wv.y +
              (double)wv.z * wv.z + (double)wv.w * wv.w;
      }
#pragma unroll
      for (int msk = 1; msk < 64; msk <<= 1) {
        dot += __shfl_xor(dot, msk, 64);
        w2 += __shfl_xor(w2, msk, 64);
      }
      double sq = x2 + w2 - 2.0 * dot;   // identical on all lanes
      if (sq < best || (sq == best && col < bestc)) { best = sq; bestc = col; }
    }
  }

  if (L == 0) out_w[b] = (float)bestc;  // winners as fp32 (flat fp32 buffer)
  if (Gt != nullptr) {
    // coalesced gather: out[b,:] = Gt[bestc,:]  (wave-uniform bestc)
    const float4* gsrc = (const float4*)(Gt + (size_t)bestc * OO);
    float4* gdst = (float4*)(out + (size_t)b * OO);
#pragma unroll
    for (int j = 0; j < 4; ++j) {
      int q = L + 64 * j;
      if (q < OO / 4) gdst[q] = gsrc[q];
    }
  } else {
    // fallback: strided gather from G
#pragma unroll 1
    for (int j = 0; j < 16; ++j) {
      int o = L + 64 * j;
      if (o < OO) out[(size_t)b * OO + o] = G[(size_t)o * HH + bestc];
    }
  }
}

extern "C" void kernel_launch(void* const* d_in, const int* in_sizes, int n_in,
                              void* d_out, int out_size, void* d_ws, size_t ws_size,
                              hipStream_t stream) {
  const float* x  = (const float*)d_in[0];  // [4096][1024]
  const float* kw = (const float*)d_in[1];  // [8192][1024]
  const float* gw = (const float*)d_in[2];  // [1000][8192]
  float* out = (float*)d_out;               // [4096*1000] output ++ [4096] winners
  float* out_w = out + (size_t)BB * OO;

  const size_t MB = 1024 * 1024;
  char* ws = (char*)d_ws;
  uint8_t* xq = (uint8_t*)(ws);             // 4 MB
  uint8_t* kq = (uint8_t*)(ws + 4 * MB);    // 8 MB
  uint4*   pk = (uint4*)(ws + 12 * MB);     // 4 MB
  float*   Gt = (float*)(ws + 16 * MB);     // 32.77 MB
  const size_t need = 16 * MB + sizeof(float) * (size_t)HH * OO;
  float* GtArg = (ws_size >= need) ? Gt : nullptr;

  // 1) fp32 -> fp8 e4m3 (4 rows/block) + parallel G transpose tiles
  int cvt_blocks = (BB + HH) / 4 + (GtArg ? 2048 : 0);
  cvt_kernel<<<cvt_blocks, 256, 0, stream>>>(x, kw, xq, kq, gw, GtArg);

  // 2) MX-fp8 MFMA GEMM + top-2 keys per 64-col half
  dim3 g(HH / BN, BB / BM);  // (64, 32)
  gemm_top2<<<g, 256, 0, stream>>>(xq, kq, pk);

  // 3) wave-per-row exact fp64 refinement -> winners, fused coalesced gather
  select_kernel<<<BB / 4, 256, 0, stream>>>(x, kw, pk, GtArg, gw, out, out_w);
}

// Round 2
// 218.868 us; speedup vs baseline: 1.1290x; 1.1290x over previous
//
#include <hip/hip_runtime.h>
#include <hip/hip_bf16.h>
#include <hip/hip_fp16.h>

// Problem: B=4096, D=1024, H=8192, O=1000
//   winners[b] = argmin_h ||x_b - k_h||  (== argmax dot, k rows unit-norm)
//   output[b,o] = G[o, winners[b]]
// Pipeline (3 dispatches; measured fixed replay overhead ~75 us):
//   1) cvt: fp32 -> fp8(e4m3) for x,kw (4 rows/block) + parallel G->Gt transpose
//   2) gemm_top2: fp8 MFMA scores (16x16x32_fp8_fp8). Block 256x128, BK=64,
//      4 waves with 128x64 wave-tile (acc[8][4] in AGPRs -> 0.375 ds_reads per
//      MFMA vs 0.5 at 64x64; half the block-iters of the 128^2 config).
//      16B-granular XOR-swizzled LDS, 2-way-floor ds_read_b64. XCD-aware block
//      swizzle: each XCD owns an 8-wide n-slice (B 1MB + A 4MB ~ L2-resident).
//      Top-2 packed keys per (row, 64-col half) -> uint4 per (row, 128-tile).
//   3) select: wave-per-row exact fp64 refinement (margin 0.35 >> fp8 dot err
//      ~0.05) + fused coalesced gather.

#define BB 4096
#define DD 1024
#define HH 8192
#define OO 1000

#define BM 256
#define BN 128
#define BK 64          // bytes == elements (fp8)
#define NTILES (HH / BN)   // 64

typedef _Float16 f16;
typedef float f32x4 __attribute__((ext_vector_type(4)));

typedef __attribute__((address_space(3))) uint32_t lds_u32_t;
typedef __attribute__((address_space(1))) uint32_t glb_u32_t;

// ---- packed key: monotone(float) with low 7 bits = tile-local column ----
__device__ __forceinline__ uint32_t packkey(float v, int col) {
  uint32_t u = __float_as_uint(v);
  uint32_t mask = (uint32_t)((int32_t)u >> 31) | 0x80000000u;
  u ^= mask;                       // monotone: bigger float -> bigger uint
  return (u & 0xFFFFFF80u) | (uint32_t)col;
}
__device__ __forceinline__ float unpackval(uint32_t k) {
  uint32_t u = k & 0xFFFFFF80u;
  uint32_t mask = (k & 0x80000000u) ? 0x80000000u : 0xFFFFFFFFu;
  return __uint_as_float(u ^ mask);
}
__device__ __forceinline__ void kmerge(uint32_t& k1, uint32_t& k2,
                                       uint32_t o1, uint32_t o2) {
  uint32_t mn = min(k1, o1);
  uint32_t alt = (k1 > o1) ? k2 : o2;
  k1 = max(k1, o1);
  k2 = max(mn, alt);
}

// -------- cvt: fp32 -> fp8 e4m3 (4 rows/block) + parallel transpose ---------
// blocks [0, 3072): 4 rows each of x (rows 0..BB-1) then kw (rows BB..BB+HH-1)
// blocks [3072, 3072+2048): 4 parallel 32x32 transpose tiles of G -> Gt
__global__ __launch_bounds__(256) void cvt_kernel(
    const float* __restrict__ x, const float* __restrict__ kw,
    uint8_t* __restrict__ xq, uint8_t* __restrict__ kq,
    const float* __restrict__ G, float* __restrict__ Gt) {
  const int tid = threadIdx.x;
  const int blk = blockIdx.x;
  __shared__ float tile[32][33];
  if (blk < (BB + HH) / 4) {
#pragma unroll
    for (int i = 0; i < 4; ++i) {
      int r = blk * 4 + i;
      const float* src = (r < BB) ? (x + (size_t)r * DD)
                                  : (kw + (size_t)(r - BB) * DD);
      uint8_t* dst = (r < BB) ? (xq + (size_t)r * DD)
                              : (kq + (size_t)(r - BB) * DD);
      float4 v = ((const float4*)src)[tid];
      int p = 0;
      p = __builtin_amdgcn_cvt_pk_fp8_f32(v.x, v.y, p, false);  // bytes 0,1
      p = __builtin_amdgcn_cvt_pk_fp8_f32(v.z, v.w, p, true);   // bytes 2,3
      ((int*)dst)[tid] = p;
    }
  } else {
    if (Gt == nullptr) return;
    const int tb = blk - (BB + HH) / 4;
    const int tx = tid & 31;
    const int ty = tid >> 5;  // 0..7
#pragma unroll 1
    for (int j4 = 0; j4 < 4; ++j4) {
      int tile_id = tb * 4 + j4;       // 0..8191
      int h0 = (tile_id >> 5) * 32;
      int o0 = (tile_id & 31) * 32;
      __syncthreads();
#pragma unroll
      for (int j = 0; j < 4; ++j) {
        int o = o0 + ty + j * 8;
        if (o < OO) tile[ty + j * 8][tx] = G[(size_t)o * HH + h0 + tx];
      }
      __syncthreads();
#pragma unroll
      for (int j = 0; j < 4; ++j) {
        int o = o0 + tx;
        int h = h0 + ty + j * 8;
        if (o < OO) Gt[(size_t)h * OO + o] = tile[tx][ty + j * 8];
      }
    }
  }
}

// ---------------- GEMM (fp8 scores) + top-2 keys per half-tile --------------
// A = xq [B][D] fp8, Bt = kq [H][D] fp8 (NT). Block: 256x128 C-tile, BK=64
// (16 K-iters; per wave per iter: 24 ds_read_b64 + 64 MFMA; 6 gl_lds/thread).
// Wave grid 2x2, wave-tile 128x64 (wr = w>>1 row half, wc = w&1 col half).
// LDS swizzle at 16B granularity: LDS 16B-chunk (row, c16) holds source chunk
// c16 ^ ((row>>1)&3). Writer (global_load_lds) stays lane-linear in LDS with
// 16B-contiguous sources; reader (8B frags) 2-way floor (q&1 fixed/quarter).
__global__ __launch_bounds__(256, 2) void gemm_top2(
    const uint8_t* __restrict__ A, const uint8_t* __restrict__ Bt,
    uint4* __restrict__ pk) {
  __shared__ __align__(16) uint8_t sA[BM * BK];  // 16 KB
  __shared__ __align__(16) uint8_t sB[BN * BK];  // 8 KB
  __shared__ uint2 mk[BM][2];                    // 4 KB

  const int tid = threadIdx.x;
  const int w = tid >> 6;       // wave 0..3
  const int L = tid & 63;       // lane

  // XCD-aware bijective remap: grid 64x16 = 1024 blocks = 8 XCD * 128.
  // XCD c (= linear bid & 7) owns n-tiles [8c, 8c+8) across all m.
  const int bid = blockIdx.y * gridDim.x + blockIdx.x;
  const int c8 = bid & 7;
  const int tt = bid >> 3;           // 0..127
  const int nx = c8 * 8 + (tt & 7);  // 0..63
  const int my = tt >> 3;            // 0..15
  const int m0 = my * BM;
  const int n0 = nx * BN;

  const int wr = w >> 1;  // 0,1: row half (128 rows)
  const int wc = w & 1;   // 0,1: col half (64 cols)

  f32x4 acc[8][4];
#pragma unroll
  for (int i = 0; i < 8; ++i)
#pragma unroll
    for (int j = 0; j < 4; ++j) {
      acc[i][j][0] = 0.f; acc[i][j][1] = 0.f; acc[i][j][2] = 0.f; acc[i][j][3] = 0.f;
    }

  const int lm = L & 15;    // fragment row within 16
  const int lq = L >> 4;    // quad

  // staging: sA = 1024 16B-chunks (4/thread), sB = 512 (2/thread).
  // chunk c: row = c>>2, c16 = c&3, source 16B-chunk = c16 ^ ((row>>1)&3).
  const uint8_t* pA[4]; int dA[4];
#pragma unroll
  for (int j = 0; j < 4; ++j) {
    int c = tid + 256 * j;
    int r = c >> 2;
    int so = ((c & 3) ^ ((r >> 1) & 3)) * 16;
    pA[j] = A + (size_t)(m0 + r) * DD + so;
    dA[j] = c * 16;
  }
  const uint8_t* pB[2]; int dB[2];
#pragma unroll
  for (int j = 0; j < 2; ++j) {
    int c = tid + 256 * j;
    int r = c >> 2;
    int so = ((c & 3) ^ ((r >> 1) & 3)) * 16;
    pB[j] = Bt + (size_t)(n0 + r) * DD + so;
    dB[j] = c * 16;
  }

  // fragment read: logical 8B-chunk q = khalf*4 + lq of row; LDS byte =
  // row*64 + ((q>>1) ^ t2)*16 + (q&1)*8, t2 = (row>>1)&3 = (lm>>1)&3
  // (row bases wr*128 / wc*64 and i*16 strides are 0 mod 8).
  const int t2 = (lm >> 1) & 3;
  const int raBase = (wr * 128 + lm) * BK;
  const int rbBase = (wc * 64 + lm) * BK;
  const int off0 = (((lq >> 1)) ^ t2) * 16 + (lq & 1) * 8;        // khalf 0
  const int off1 = ((2 + (lq >> 1)) ^ t2) * 16 + (lq & 1) * 8;    // khalf 1

  for (int kt = 0; kt < DD / BK; ++kt) {
    __syncthreads();  // prev compute done before overwriting LDS
#pragma unroll
    for (int j = 0; j < 4; ++j) {
      __builtin_amdgcn_global_load_lds((const glb_u32_t*)pA[j], (lds_u32_t*)(sA + dA[j]), 16, 0, 0);
      pA[j] += BK;
    }
#pragma unroll
    for (int j = 0; j < 2; ++j) {
      __builtin_amdgcn_global_load_lds((const glb_u32_t*)pB[j], (lds_u32_t*)(sB + dB[j]), 16, 0, 0);
      pB[j] += BK;
    }
    __syncthreads();  // drains vmcnt before use

    long long af[8], bf[4];
    // k-half 0
#pragma unroll
    for (int i = 0; i < 8; ++i)
      af[i] = *(const long long*)(sA + raBase + i * 16 * BK + off0);
#pragma unroll
    for (int j = 0; j < 4; ++j)
      bf[j] = *(const long long*)(sB + rbBase + j * 16 * BK + off0);
#pragma unroll
    for (int i = 0; i < 8; ++i)
#pragma unroll
      for (int j = 0; j < 4; ++j)
        acc[i][j] = __builtin_amdgcn_mfma_f32_16x16x32_fp8_fp8(af[i], bf[j], acc[i][j], 0, 0, 0);
    // k-half 1
#pragma unroll
    for (int i = 0; i < 8; ++i)
      af[i] = *(const long long*)(sA + raBase + i * 16 * BK + off1);
#pragma unroll
    for (int j = 0; j < 4; ++j)
      bf[j] = *(const long long*)(sB + rbBase + j * 16 * BK + off1);
#pragma unroll
    for (int i = 0; i < 8; ++i)
#pragma unroll
      for (int j = 0; j < 4; ++j)
        acc[i][j] = __builtin_amdgcn_mfma_f32_16x16x32_fp8_fp8(af[i], bf[j], acc[i][j], 0, 0, 0);
  }

  // Epilogue: per-row top-2 over this wave's 64-col half (packed keys).
  // C/D layout (16x16x32): col = lane&15, row = (lane>>4)*4 + reg.
  const int col0 = wc * 64 + lm;
#pragma unroll
  for (int i = 0; i < 8; ++i) {
#pragma unroll
    for (int r = 0; r < 4; ++r) {
      uint32_t k1 = 0, k2 = 0;
#pragma unroll
      for (int j = 0; j < 4; ++j) {
        uint32_t kj = packkey(acc[i][j][r], col0 + j * 16);
        if (kj > k1) { k2 = k1; k1 = kj; }
        else k2 = max(k2, kj);
      }
#pragma unroll
      for (int msk = 1; msk < 16; msk <<= 1) {
        uint32_t o1 = (uint32_t)__shfl_xor((int)k1, msk, 64);
        uint32_t o2 = (uint32_t)__shfl_xor((int)k2, msk, 64);
        kmerge(k1, k2, o1, o2);
      }
      if (lm == 0) {
        int rl = wr * 128 + i * 16 + lq * 4 + r;
        mk[rl][wc] = make_uint2(k1, k2);
      }
    }
  }
  __syncthreads();
  {
    uint2 a = mk[tid][0], b = mk[tid][1];  // top-2 per 64-col half
    pk[(size_t)(m0 + tid) * NTILES + nx] = make_uint4(a.x, a.y, b.x, b.y);
  }
}

// ------- select: wave-per-row exact fp64 refinement + fused gather ----------
// One 64-lane wave per x-row; 4 rows per 256-thread block. No __syncthreads.
__global__ __launch_bounds__(256) void select_kernel(
    const float* __restrict__ x, const float* __restrict__ kw,
    const uint4* __restrict__ pk,
    const float* __restrict__ Gt, const float* __restrict__ G,
    float* __restrict__ out, float* __restrict__ out_w) {
  const int b = blockIdx.x * 4 + (threadIdx.x >> 6);
  const int L = threadIdx.x & 63;

  // x row: 16 floats/lane (4 x float4, coalesced)
  const float4* x4 = (const float4*)(x + (size_t)b * DD);
  float4 xv[4];
#pragma unroll
  for (int j = 0; j < 4; ++j) xv[j] = x4[L + 64 * j];

  // keys of tile L: top-2 of each 64-col half (k.x>=k.y, k.z>=k.w)
  uint4 kp = pk[(size_t)b * NTILES + L];

  // x2 in fp64 (xor-reduce -> all lanes hold total)
  double x2 = 0.0;
#pragma unroll
  for (int j = 0; j < 4; ++j)
    x2 += (double)xv[j].x * xv[j].x + (double)xv[j].y * xv[j].y +
          (double)xv[j].z * xv[j].z + (double)xv[j].w * xv[j].w;
#pragma unroll
  for (int msk = 1; msk < 64; msk <<= 1) x2 += __shfl_xor(x2, msk, 64);

  // global max key -> margin threshold (fp8 dot err rms ~0.05; 0.35 >= 5 sigma)
  uint32_t m = max(kp.x, kp.z);
#pragma unroll
  for (int msk = 1; msk < 64; msk <<= 1)
    m = max(m, (uint32_t)__shfl_xor((int)m, msk, 64));
  const uint32_t thrk = packkey(unpackval(m) - 0.35f, 0);

  unsigned long long cand[4];
  cand[0] = __ballot(kp.x >= thrk);
  cand[1] = __ballot(kp.y >= thrk);
  cand[2] = __ballot(kp.z >= thrk);
  cand[3] = __ballot(kp.w >= thrk);

  double best = 1e300;
  int bestc = 0x7fffffff;
#pragma unroll 1
  for (int pass = 0; pass < 4; ++pass) {
    unsigned long long bits = cand[pass];
    uint32_t mykey = (pass == 0) ? kp.x : (pass == 1) ? kp.y
                    : (pass == 2) ? kp.z : kp.w;
    while (bits) {
      int tt = __ffsll((long long)bits) - 1;   // candidate's tile = lane tt
      bits &= bits - 1;
      uint32_t kbt = (uint32_t)__shfl((int)mykey, tt, 64);
      int col = tt * 128 + (int)(kbt & 127u);
      const float4* k4 = (const float4*)(kw + (size_t)col * DD);
      double dot = 0.0, w2 = 0.0;
#pragma unroll
      for (int j = 0; j < 4; ++j) {
        float4 wv = k4[L + 64 * j];
        dot += (double)xv[j].x * wv.x + (double)xv[j].y * wv.y +
               (double)xv[j].z * wv.z + (double)xv[j].w * wv.w;
        w2 += (double)wv.x * wv.x + (double)wv.y * wv.y +
              (double)wv.z * wv.z + (double)wv.w * wv.w;
      }
#pragma unroll
      for (int msk = 1; msk < 64; msk <<= 1) {
        dot += __shfl_xor(dot, msk, 64);
        w2 += __shfl_xor(w2, msk, 64);
      }
      double sq = x2 + w2 - 2.0 * dot;   // identical on all lanes
      if (sq < best || (sq == best && col < bestc)) { best = sq; bestc = col; }
    }
  }

  if (L == 0) out_w[b] = (float)bestc;  // winners as fp32 (flat fp32 buffer)
  if (Gt != nullptr) {
    // coalesced gather: out[b,:] = Gt[bestc,:]  (wave-uniform bestc)
    const float4* gsrc = (const float4*)(Gt + (size_t)bestc * OO);
    float4* gdst = (float4*)(out + (size_t)b * OO);
#pragma unroll
    for (int j = 0; j < 4; ++j) {
      int q = L + 64 * j;
      if (q < OO / 4) gdst[q] = gsrc[q];
    }
  } else {
    // fallback: strided gather from G
#pragma unroll 1
    for (int j = 0; j < 16; ++j) {
      int o = L + 64 * j;
      if (o < OO) out[(size_t)b * OO + o] = G[(size_t)o * HH + bestc];
    }
  }
}

extern "C" void kernel_launch(void* const* d_in, const int* in_sizes, int n_in,
                              void* d_out, int out_size, void* d_ws, size_t ws_size,
                              hipStream_t stream) {
  const float* x  = (const float*)d_in[0];  // [4096][1024]
  const float* kw = (const float*)d_in[1];  // [8192][1024]
  const float* gw = (const float*)d_in[2];  // [1000][8192]
  float* out = (float*)d_out;               // [4096*1000] output ++ [4096] winners
  float* out_w = out + (size_t)BB * OO;

  const size_t MB = 1024 * 1024;
  char* ws = (char*)d_ws;
  uint8_t* xq = (uint8_t*)(ws);             // 4 MB
  uint8_t* kq = (uint8_t*)(ws + 4 * MB);    // 8 MB
  uint4*   pk = (uint4*)(ws + 12 * MB);     // 4 MB
  float*   Gt = (float*)(ws + 16 * MB);     // 32.77 MB
  const size_t need = 16 * MB + sizeof(float) * (size_t)HH * OO;
  float* GtArg = (ws_size >= need) ? Gt : nullptr;

  // 1) fp32 -> fp8 e4m3 (4 rows/block) + parallel G transpose tiles
  int cvt_blocks = (BB + HH) / 4 + (GtArg ? 2048 : 0);
  cvt_kernel<<<cvt_blocks, 256, 0, stream>>>(x, kw, xq, kq, gw, GtArg);

  // 2) fp8 MFMA GEMM + top-2 keys per 64-col half
  dim3 g(HH / BN, BB / BM);  // (64, 16)
  gemm_top2<<<g, 256, 0, stream>>>(xq, kq, pk);

  // 3) wave-per-row exact fp64 refinement -> winners, fused coalesced gather
  select_kernel<<<BB / 4, 256, 0, stream>>>(x, kw, pk, GtArg, gw, out, out_w);
}